// Round 6
// baseline (741.339 us; speedup 1.0000x reference)
//
#include <hip/hip_runtime.h>
#include <hip/hip_bf16.h>

#define BATCH 2
#define NPB   2048
#define NPTS  4096   // BATCH*NPB
#define KNB   27
#define FCATC 1440
#define CSTRIDE 1696   // channel stride for slot partial sums (1440 + 256)
#define NSLOT 32
#define PBATCH 4       // points per gather block (atomic-traffic reduction)

// weight-plane segment offsets (elements): layer1 2*192x96, layer2 2*384x192, layer3 2*768x384, final 256x1440
#define WOFF_L1 0
#define WOFF_L2 36864
#define WOFF_L3 184320
#define WOFF_F  774144
#define WTOTAL  1142784

typedef __hip_bfloat16 bf16;
typedef __attribute__((ext_vector_type(8))) short short8;   // 8 bf16 = 4 VGPRs (MFMA A/B frag)
typedef __attribute__((ext_vector_type(4))) float f32x4;    // MFMA C/D frag
typedef __attribute__((ext_vector_type(2))) short s16x2;    // 2 bf16 = 4B vector

__device__ __forceinline__ float b2f(bf16 v) { return __bfloat162float(v); }

// split fp32 into hi/lo bf16 pair (hi + lo ~ 16 mantissa bits)
__device__ __forceinline__ void split_bf16(float v, bf16& h, bf16& l) {
    h = __float2bfloat16(v);
    l = __float2bfloat16(v - b2f(h));
}

// load input element i from buffer p whose dtype is fp32 (f32=1) or bf16 (f32=0)
__device__ __forceinline__ float ldin(const void* p, size_t i, int f32) {
    return f32 ? ((const float*)p)[i] : b2f(((const bf16*)p)[i]);
}

// async global->LDS 16B: lane writes lds_base + lane*16 (wave-uniform base, per-lane global)
__device__ __forceinline__ void gl16(const bf16* g, bf16* l) {
    __builtin_amdgcn_global_load_lds(
        (const __attribute__((address_space(1))) unsigned int*)g,
        (__attribute__((address_space(3))) unsigned int*)l,
        16, 0, 0);
}

// ---------------- init: zero slot accumulators + counters/enc + dtype-detect + convert x ----------------
__global__ void k_init(const void* __restrict__ x, int* __restrict__ flag,
                       float* __restrict__ xf, float* __restrict__ slots,
                       int* __restrict__ cnt, int* __restrict__ enc) {
    if (blockIdx.x < 424) {
        slots[blockIdx.x * 256 + threadIdx.x] = 0.f;
        return;
    }
    // detect block also zeroes fusion counters + encoded-max buffer
    if (threadIdx.x < 8) cnt[threadIdx.x] = 0;
    for (int i = threadIdx.x; i < 512; i += 256) enc[i] = 0;   // 0 == below every encoded float
    __shared__ int s;
    if (threadIdx.x == 0) s = 0;
    __syncthreads();
    const bf16* xb = (const bf16*)x;
    int local = 0;
    for (int i = threadIdx.x; i < NPTS * 3; i += 256) {
        float v = b2f(xb[i]);
        if (!(fabsf(v) < 1e4f)) local = 1;   // catches NaN/Inf/huge -> underlying fp32
    }
    if (local) s = 1;
    __syncthreads();
    int f32 = s;
    if (threadIdx.x == 0) flag[0] = f32;
    for (int i = threadIdx.x; i < NPTS * 3; i += 256) xf[i] = ldin(x, i, f32);
}

// ---------------- KNN via 2-pass radix-select (16-bit prefix) + tie resolution ----------------
__global__ __launch_bounds__(256) void k_knn(const float* __restrict__ x, int* __restrict__ idx) {
    __shared__ uint hist4[4][260];   // per-wave copies, padded
    __shared__ uint hist[256];
    __shared__ uint tkey[NPB];
    __shared__ int  tix[NPB];
    __shared__ uint s_phigh;
    __shared__ int  s_rem, s_outcnt, s_tiecnt;

    int bn = blockIdx.x, b = bn >> 11, n = bn & (NPB - 1);
    int tid = threadIdx.x;
    int wv = tid >> 6;
    const float* xb = x + (size_t)b * NPB * 3;
    float cx = xb[n * 3 + 0], cy = xb[n * 3 + 1], cz = xb[n * 3 + 2];
    float cc = cx * cx + cy * cy + cz * cz;

    uint u[8];
    #pragma unroll
    for (int j = 0; j < 8; j++) {
        int m = j * 256 + tid;
        float mx = xb[m * 3 + 0], my = xb[m * 3 + 1], mz = xb[m * 3 + 2];
        float d = 2.f * (cx * mx + cy * my + cz * mz) - cc - (mx * mx + my * my + mz * mz);
        uint s = __float_as_uint(d);
        u[j] = (s & 0x80000000u) ? ~s : (s | 0x80000000u);
    }
    if (tid == 0) { s_phigh = 0; s_rem = KNB; s_outcnt = 0; s_tiecnt = 0; }

    for (int pass = 0; pass < 2; pass++) {
        int shift = 24 - pass * 8;
        hist[tid] = 0;
        for (int i = tid; i < 4 * 260; i += 256) ((uint*)hist4)[i] = 0;
        __syncthreads();
        uint phigh = s_phigh;
        #pragma unroll
        for (int j = 0; j < 8; j++) {
            bool in = (pass == 0) || ((u[j] >> (shift + 8)) == phigh);
            if (in) atomicAdd(&hist4[wv][(u[j] >> shift) & 0xFFu], 1u);
        }
        __syncthreads();
        hist[tid] = hist4[0][tid] + hist4[1][tid] + hist4[2][tid] + hist4[3][tid];
        __syncthreads();
        if (tid < 64) {
            int L = tid;
            uint c0 = hist[L * 4 + 0], c1 = hist[L * 4 + 1], c2 = hist[L * 4 + 2], c3 = hist[L * 4 + 3];
            uint s = c0 + c1 + c2 + c3;
            uint acc = s;
            #pragma unroll
            for (int off = 1; off < 64; off <<= 1) {
                uint t = __shfl_down(acc, off);
                if (L + off < 64) acc += t;
            }
            uint excl = acc - s;
            int rem = s_rem;
            if ((int)excl < rem && (int)acc >= rem) {
                uint cs[4] = { c0, c1, c2, c3 };
                uint cum = excl;
                int bsel = 0; uint hb = 0;
                #pragma unroll
                for (int q = 3; q >= 0; q--) {
                    if ((int)cum < rem && (int)(cum + cs[q]) >= rem && hb == 0u && bsel == 0) {
                        bsel = L * 4 + q; hb = cs[q]; cum += cs[q];
                    } else if (bsel == 0 && hb == 0u) {
                        cum += cs[q];
                    }
                }
                int strictlyAbove = (int)(cum - hb);
                s_rem = rem - strictlyAbove;
                s_phigh = (phigh << 8) | (uint)bsel;
            }
        }
        __syncthreads();
    }

    uint T16 = s_phigh;   // 16-bit prefix of the 27th-largest key
    #pragma unroll
    for (int j = 0; j < 8; j++) {
        int m = j * 256 + tid;
        uint hi = u[j] >> 16;
        if (hi > T16) {
            int p = atomicAdd(&s_outcnt, 1);
            idx[bn * KNB + p] = b * NPB + m;
        } else if (hi == T16) {
            int p = atomicAdd(&s_tiecnt, 1);
            tkey[p] = u[j];
            tix[p] = m;
        }
    }
    __syncthreads();
    int outcnt = s_outcnt, rem = s_rem, tiecnt = s_tiecnt;
    if (tiecnt == rem) {
        if (tid < rem) idx[bn * KNB + outcnt + tid] = b * NPB + tix[tid];
    } else if (tid == 0) {
        for (int t = 0; t < rem; t++) {
            int bi = 0;
            for (int q = 1; q < tiecnt; q++)
                if (tkey[q] > tkey[bi] || (tkey[q] == tkey[bi] && tix[q] < tix[bi])) bi = q;
            idx[bn * KNB + outcnt + t] = b * NPB + tix[bi];
            tkey[bi] = 0; tix[bi] = 0x7fffffff;
        }
    }
}

// ---------------- layer0 direct: u -> Ub bf16, v -> Vf f32 (Co=96) ----------------
__global__ void k_l0(const float* __restrict__ xf, const void* __restrict__ W,
                     const int* __restrict__ flag, bf16* __restrict__ Ub, float* __restrict__ Vf) {
    int i = blockIdx.x * 256 + threadIdx.x;
    if (i >= NPTS * 192) return;
    int bn = i / 192, o = i % 192;
    int f32 = flag[0];
    float x0 = xf[bn * 3 + 0], x1 = xf[bn * 3 + 1], x2 = xf[bn * 3 + 2];
    if (o < 96) {
        float r = x0 * ldin(W, o * 6 + 0, f32) + x1 * ldin(W, o * 6 + 1, f32) + x2 * ldin(W, o * 6 + 2, f32);
        Ub[(size_t)bn * 96 + o] = __float2bfloat16(r);
    } else {
        int oo = o - 96;
        float w0 = ldin(W, oo * 6 + 3, f32) - ldin(W, oo * 6 + 0, f32);
        float w1 = ldin(W, oo * 6 + 4, f32) - ldin(W, oo * 6 + 1, f32);
        float w2 = ldin(W, oo * 6 + 5, f32) - ldin(W, oo * 6 + 2, f32);
        Vf[(size_t)bn * 96 + oo] = x0 * w0 + x1 * w1 + x2 * w2;
    }
}

// ---------------- ALL weight transforms in one kernel -> contiguous hi/lo planes ----------------
__global__ void k_wt_all(const void* __restrict__ W1, const void* __restrict__ W2,
                         const void* __restrict__ W3, const void* __restrict__ W4,
                         const int* __restrict__ flag,
                         bf16* __restrict__ Wh, bf16* __restrict__ Wl) {
    int i = blockIdx.x * 256 + threadIdx.x;
    if (i >= WTOTAL) return;
    int f32 = flag[0];
    float w;
    if (i < WOFF_L2) {                     // layer1: Cin=96, Co=192, 2Cin=192
        int row = i / 96, c = i % 96;
        w = (row < 192) ? ldin(W1, (size_t)row * 192 + c, f32)
                        : ldin(W1, (size_t)(row - 192) * 192 + 96 + c, f32)
                          - ldin(W1, (size_t)(row - 192) * 192 + c, f32);
    } else if (i < WOFF_L3) {              // layer2: Cin=192, Co=384, 2Cin=384
        int j = i - WOFF_L2;
        int row = j / 192, c = j % 192;
        w = (row < 384) ? ldin(W2, (size_t)row * 384 + c, f32)
                        : ldin(W2, (size_t)(row - 384) * 384 + 192 + c, f32)
                          - ldin(W2, (size_t)(row - 384) * 384 + c, f32);
    } else if (i < WOFF_F) {               // layer3: Cin=384, Co=768, 2Cin=768
        int j = i - WOFF_L3;
        int row = j / 384, c = j % 384;
        w = (row < 768) ? ldin(W3, (size_t)row * 768 + c, f32)
                        : ldin(W3, (size_t)(row - 768) * 768 + 384 + c, f32)
                          - ldin(W3, (size_t)(row - 768) * 768 + c, f32);
    } else {                               // final: 256 x 1440 direct
        int j = i - WOFF_F;
        w = ldin(W4, j, f32);
    }
    bf16 h, l; split_bf16(w, h, l);
    Wh[i] = h; Wl[i] = l;
}

// ---------------- split-precision MFMA GEMM: C = (Ah+Al) * (Bh+Bl)^T, ~fp32 accuracy ----------------
// Asymmetric tile TM x TN (128x64 for wide layers -> 768/640 blocks, 2.5-3/CU; 64x64 skinny).
// 2-phase pipeline: double-buffered LDS, prefetch next K-step's gl16 BEFORE computing current,
// ONE __syncthreads per step. Bank-conflict fix (rule #21, both-sides): source takes global
// 16B-slot (slot ^ ((row>>1)&3)); frag read XORs the same -> 8-way conflict becomes 2-way (free).
// Cosplit>0: cols [0,Cosplit)->Cu bf16, rest->Cv f32; Cosplit==0: f32 split-K plane write (Cz).
template<int TM, int TN>
__global__ __launch_bounds__(256) void k_gemm_mfma(const bf16* __restrict__ Ah, const bf16* __restrict__ Al,
                                                   int lda, int aoff,
                                                   const bf16* __restrict__ Bh, const bf16* __restrict__ Bl,
                                                   int K, bf16* __restrict__ Cu, float* __restrict__ Cv,
                                                   int Cosplit, int ldc, int ksz, int zstride) {
    constexpr int FRM  = TM / 32;          // A frags per wave
    constexpr int FRN  = TN / 32;          // B frags per wave
    constexpr int ISSA = TM / 64;          // gl16 issues per A array per thread
    constexpr int ISSB = TN / 64;          // gl16 issues per B array per thread
    constexpr int MY   = (NPTS / TM) / 8;  // m-tiles per stripe (pow2)
    __shared__ __align__(16) bf16 Ash[2][TM][32];   // linear (global_load_lds needs contiguous dest)
    __shared__ __align__(16) bf16 Asl[2][TM][32];
    __shared__ __align__(16) bf16 Bsh[2][TN][32];
    __shared__ __align__(16) bf16 Bsl[2][TN][32];
    int tid = threadIdx.x;
    int wave = tid >> 6, lane = tid & 63;
    int wm = wave >> 1, wn = wave & 1;
    int quad = lane >> 4, l15 = lane & 15;
    int Lxy = blockIdx.y * gridDim.x + blockIdx.x;
    int stripe = Lxy & 7;
    int w = Lxy >> 3;
    int mb = stripe * MY + (w & (MY - 1));
    int nb = w / MY;
    int m0 = mb * TM, n0 = nb * TN;
    int kbase = blockIdx.z * ksz;
    float* Cz = Cv + (size_t)blockIdx.z * zstride;

    // staging geometry: chunk c covers LDS row c>>2, physical 16B slot c&3; the SOURCE takes
    // global slot (c&3)^((row>>1)&3) so that a swizzled frag read is conflict-free.
    int ra_s[ISSA], ca_s[ISSA];
    #pragma unroll
    for (int i = 0; i < ISSA; i++) {
        int c = wave * 64 + lane + i * 256;
        ra_s[i] = c >> 2;
        ca_s[i] = (((c & 3) ^ ((c >> 3) & 3)) << 3);
    }
    int rb_s[ISSB], cb_s[ISSB];
    #pragma unroll
    for (int i = 0; i < ISSB; i++) {
        int c = wave * 64 + lane + i * 256;
        rb_s[i] = c >> 2;
        cb_s[i] = (((c & 3) ^ ((c >> 3) & 3)) << 3);
    }

    auto STAGE = [&](int buf, int k0) {
        #pragma unroll
        for (int i = 0; i < ISSA; i++) {
            size_t ga = (size_t)(m0 + ra_s[i]) * lda + aoff + k0 + ca_s[i];
            gl16(Ah + ga, &Ash[buf][0][0] + wave * 512 + i * 2048);   // wave-uniform LDS base
            gl16(Al + ga, &Asl[buf][0][0] + wave * 512 + i * 2048);
        }
        #pragma unroll
        for (int i = 0; i < ISSB; i++) {
            size_t gb = (size_t)(n0 + rb_s[i]) * K + k0 + cb_s[i];
            gl16(Bh + gb, &Bsh[buf][0][0] + wave * 512 + i * 2048);
            gl16(Bl + gb, &Bsl[buf][0][0] + wave * 512 + i * 2048);
        }
    };

    int nsteps = ksz >> 5;
    f32x4 acc[FRM][FRN] = {};
    STAGE(0, kbase);
    __syncthreads();
    int cur = 0;
    for (int t = 0; t < nsteps; t++) {
        if (t + 1 < nsteps) STAGE(cur ^ 1, kbase + ((t + 1) << 5));   // prefetch next step
        short8 ahf[FRM], alf[FRM], bhf[FRN], blf[FRN];
        #pragma unroll
        for (int mt = 0; mt < FRM; mt++) {
            int rr = wm * (TM / 2) + mt * 16 + l15;
            int qs = (quad ^ ((rr >> 1) & 3)) * 8;
            ahf[mt] = *(const short8*)&Ash[cur][rr][qs];
            alf[mt] = *(const short8*)&Asl[cur][rr][qs];
        }
        #pragma unroll
        for (int nt = 0; nt < FRN; nt++) {
            int rr = wn * (TN / 2) + nt * 16 + l15;
            int qs = (quad ^ ((rr >> 1) & 3)) * 8;
            bhf[nt] = *(const short8*)&Bsh[cur][rr][qs];
            blf[nt] = *(const short8*)&Bsl[cur][rr][qs];
        }
        #pragma unroll
        for (int mt = 0; mt < FRM; mt++) {
            #pragma unroll
            for (int nt = 0; nt < FRN; nt++) {
                acc[mt][nt] = __builtin_amdgcn_mfma_f32_16x16x32_bf16(ahf[mt], blf[nt], acc[mt][nt], 0, 0, 0);
                acc[mt][nt] = __builtin_amdgcn_mfma_f32_16x16x32_bf16(alf[mt], bhf[nt], acc[mt][nt], 0, 0, 0);
                acc[mt][nt] = __builtin_amdgcn_mfma_f32_16x16x32_bf16(ahf[mt], bhf[nt], acc[mt][nt], 0, 0, 0);
            }
        }
        __syncthreads();   // drains prefetch vmcnt + lgkm; orders buffer reuse
        cur ^= 1;
    }
    #pragma unroll
    for (int mt = 0; mt < FRM; mt++) {
        #pragma unroll
        for (int nt = 0; nt < FRN; nt++) {
            int col = n0 + wn * (TN / 2) + nt * 16 + l15;
            #pragma unroll
            for (int i = 0; i < 4; i++) {
                int row = m0 + wm * (TM / 2) + mt * 16 + quad * 4 + i;
                if (Cosplit > 0) {
                    if (col < Cosplit) Cu[(size_t)row * Cosplit + col] = __float2bfloat16(acc[mt][nt][i]);
                    else               Cv[(size_t)row * Cosplit + col - Cosplit] = acc[mt][nt][i];
                } else {
                    Cz[(size_t)row * ldc + col] = acc[mt][nt][i];
                }
            }
        }
    }
}

// ---------------- fused gather + last-block scale/shift ----------------
// XCD-batch partition: with the observed round-robin block->XCD mapping (bid%8), XCDs 0-3 handle
// batch 0, XCDs 4-7 batch 1 -> each XCD's hot Ub slice is 3.1 MB (Co=768) <= 4 MiB L2 (was 6.3 MB
// thrash). Bijective remap: L bits [b10|b9..b3|b2|b1b0] -> chunk|mid|batch|low2.
// Last block (device-scope counter) computes the per-channel BN scale/shift (replaces k_scaleshift).
__global__ __launch_bounds__(256) void k_gather(const bf16* __restrict__ Ub, float* __restrict__ Vf,
                                                const int* __restrict__ idx,
                                                bf16* __restrict__ fch, bf16* __restrict__ fcl,
                                                float* __restrict__ ssum, float* __restrict__ ssq,
                                                int Co, int out_off,
                                                const void* __restrict__ g, const void* __restrict__ bb,
                                                const int* __restrict__ flag,
                                                float* __restrict__ scale, float* __restrict__ shift,
                                                float invcnt, int* __restrict__ cnt, int total) {
    __shared__ int srow[PBATCH * KNB];
    __shared__ int s_last;
    int tid = threadIdx.x;
    int L = blockIdx.y * gridDim.x + blockIdx.x;
    int batch = (L >> 2) & 1;                            // XCD-pair partition (bid%8: 0-3 vs 4-7)
    int pg = batch * 512 + (L & 3) * 128 + ((L >> 3) & 127);
    int chunk = L >> 10;                                 // channel-pair chunk
    int p0 = pg * PBATCH;
    if (tid < PBATCH * KNB) srow[tid] = idx[p0 * KNB + tid] * Co;
    __syncthreads();
    int P = Co >> 1;
    int op = chunk * 256 + tid;
    if (op < P) {
        int o = op * 2;
        int slot = pg & (NSLOT - 1);
        float s0 = 0.f, s1 = 0.f, q0 = 0.f, q1 = 0.f;
        #pragma unroll 1
        for (int p = 0; p < PBATCH; p++) {
            int bn = p0 + p;
            float2 vv = *(const float2*)&Vf[(size_t)bn * Co + o];
            float ymax0 = -INFINITY, ymax1 = -INFINITY, ymin0 = INFINITY, ymin1 = INFINITY;
            #pragma unroll
            for (int k = 0; k < KNB; k++) {
                uint wb = *(const uint*)&Ub[(size_t)srow[p * KNB + k] + o];
                float y0 = __uint_as_float(wb << 16) + vv.x;
                float y1 = __uint_as_float(wb & 0xffff0000u) + vv.y;
                ymax0 = fmaxf(ymax0, y0); ymin0 = fminf(ymin0, y0); s0 += y0; q0 += y0 * y0;
                ymax1 = fmaxf(ymax1, y1); ymin1 = fminf(ymin1, y1); s1 += y1; q1 += y1 * y1;
            }
            size_t fi = (size_t)bn * FCATC + out_off + o;
            bf16 hh[2], ll[2];
            split_bf16(ymax0, hh[0], ll[0]);
            split_bf16(ymax1, hh[1], ll[1]);
            *(s16x2*)&fch[fi] = *(const s16x2*)hh;
            *(s16x2*)&fcl[fi] = *(const s16x2*)ll;
            *(float2*)&Vf[(size_t)bn * Co + o] = make_float2(ymin0, ymin1);   // stash ymin
        }
        atomicAdd(&ssum[slot * CSTRIDE + o + 0], s0);
        atomicAdd(&ssum[slot * CSTRIDE + o + 1], s1);
        atomicAdd(&ssq [slot * CSTRIDE + o + 0], q0);
        atomicAdd(&ssq [slot * CSTRIDE + o + 1], q1);
    }
    __threadfence();                      // release: this block's sums visible before counter bump
    __syncthreads();
    if (tid == 0) s_last = (atomicAdd(cnt, 1) == total - 1);
    __syncthreads();
    if (s_last) {
        __threadfence();                  // acquire: all other blocks' sums now visible
        int f32 = flag[0];
        for (int o = tid; o < Co; o += 256) {
            float s = 0.f, q = 0.f;
            for (int c = 0; c < NSLOT; c++) { s += ssum[c * CSTRIDE + o]; q += ssq[c * CSTRIDE + o]; }
            float mean = s * invcnt;
            float var = q * invcnt - mean * mean;
            float sc = ldin(g, o, f32) * rsqrtf(var + 1e-5f);
            scale[o] = sc;
            shift[o] = ldin(bb, o, f32) - mean * sc;
        }
    }
}

// ---------------- apply BN + lrelu to the pooled value (in place in fcat hi/lo) ----------------
__global__ __launch_bounds__(256) void k_apply(const float* __restrict__ Vf,
                                               const float* __restrict__ scale, const float* __restrict__ shift,
                                               bf16* __restrict__ fch, bf16* __restrict__ fcl,
                                               int Co, int out_off) {
    int bn = blockIdx.x;
    for (int o = threadIdx.x; o < Co; o += 256) {
        float sc = scale[o], sh = shift[o];
        size_t fi = (size_t)bn * FCATC + out_off + o;
        float y = (sc >= 0.f) ? (b2f(fch[fi]) + b2f(fcl[fi]))
                              : Vf[(size_t)bn * Co + o];           // ymin if negative scale
        float z = sc * y + sh;
        z = (z >= 0.f) ? z : 0.2f * z;
        bf16 h, l; split_bf16(z, h, l);
        fch[fi] = h; fcl[fi] = l;
    }
}

// ---------------- final: reduce 5 split-K planes -> Y4 + BN stats (256 blocks x 16 points) ----------------
__global__ void k_stats_final(const float* __restrict__ part, float* __restrict__ Y,
                              float* __restrict__ ssum, float* __restrict__ ssq) {
    int o = threadIdx.x;
    int p0 = blockIdx.x * 16;
    int slot = blockIdx.x & (NSLOT - 1);
    const size_t PL = (size_t)NPTS * 256;
    float s = 0, q = 0;
    for (int p = 0; p < 16; p++) {
        size_t i = (size_t)(p0 + p) * 256 + o;
        float y = part[i] + part[i + PL] + part[i + 2 * PL] + part[i + 3 * PL] + part[i + 4 * PL];
        Y[i] = y;
        s += y; q += y * y;
    }
    atomicAdd(&ssum[slot * CSTRIDE + o], s);
    atomicAdd(&ssq [slot * CSTRIDE + o], q);
}

// ---------------- feats: final BN + lrelu + per-point write + fused global max (last block) ----------------
__global__ void k_feats(const float* __restrict__ Y, const float* __restrict__ ssum,
                        const float* __restrict__ ssq, const void* __restrict__ g,
                        const void* __restrict__ bb, const int* __restrict__ flag,
                        void* __restrict__ out, int* __restrict__ enc, int* __restrict__ cnt) {
    __shared__ int s_last;
    int o = threadIdx.x;
    int chunk = blockIdx.x;
    int bn0 = chunk * 32;
    int f32 = flag[0];
    float s = 0.f, q = 0.f;
    for (int c = 0; c < NSLOT; c++) { s += ssum[c * CSTRIDE + o]; q += ssq[c * CSTRIDE + o]; }
    float mean = s * (1.f / (float)NPTS);
    float var = q * (1.f / (float)NPTS) - mean * mean;
    float sc = ldin(g, o, f32) * rsqrtf(var + 1e-5f);
    float sh = ldin(bb, o, f32) - mean * sc;
    float best = -INFINITY;
    for (int i = 0; i < 32; i++) {
        int bn = bn0 + i;
        float z = sc * Y[(size_t)bn * 256 + o] + sh;
        z = (z >= 0.f) ? z : 0.2f * z;
        size_t oi = (size_t)BATCH * 256 + (size_t)bn * 256 + o;
        if (f32) ((float*)out)[oi] = z;
        else     ((bf16*)out)[oi] = __float2bfloat16(z);
        best = fmaxf(best, z);
    }
    // order-preserving uint encoding -> atomicMax
    uint ub = __float_as_uint(best);
    uint key = (ub & 0x80000000u) ? ~ub : (ub | 0x80000000u);
    int b = chunk >> 6;
    atomicMax((unsigned int*)&enc[b * 256 + o], key);
    __threadfence();
    if (o == 0) s_last = (atomicAdd(cnt, 1) == 127);
    __syncthreads();
    if (s_last) {
        __threadfence();
        for (int i = o; i < 512; i += 256) {
            uint k2 = ((const uint*)enc)[i];
            uint u2 = (k2 & 0x80000000u) ? (k2 & 0x7fffffffu) : ~k2;
            float v = __uint_as_float(u2);
            if (f32) ((float*)out)[i] = v;
            else     ((bf16*)out)[i] = __float2bfloat16(v);
        }
    }
}

// ---------------- launch ----------------
extern "C" void kernel_launch(void* const* d_in, const int* in_sizes, int n_in,
                              void* d_out, int out_size, void* d_ws, size_t ws_size,
                              hipStream_t stream) {
    const void* x = d_in[0];

    char* ws = (char*)d_ws;
    int*   idx    = (int*)  (ws + 0);                 // 4096*27 int
    bf16*  Ub     = (bf16*) (ws + 442368);            // 4096 x 768 bf16 (u, 6.29 MB)
    float* Vf     = (float*)(ws + 6733824);           // 4096 x 768 f32 (v/ymin, 12.58 MB)
    float* part   = (float*)(ws + 442368);            // reused after layers: 5 x 4096 x 256 f32 (21 MB)
    bf16*  fch    = (bf16*) (ws + 25608192);          // 4096 x 1440 bf16 (hi)
    bf16*  fcl    = (bf16*) (ws + 37404672);          // 4096 x 1440 bf16 (lo)
    float* Y4     = (float*)(ws + 49201152);          // 4096 x 256 f32
    bf16*  Whall  = (bf16*) (ws + 53395456);          // WTOTAL bf16 (hi planes, 2.29 MB)
    bf16*  Wlall  = (bf16*) (ws + 55681024);          // WTOTAL bf16 (lo planes)
    float* slots  = (float*)(ws + 57966592);          // 2 x 32 x 1696 f32 (434176 B)
    float* ssum   = slots;
    float* ssq    = slots + NSLOT * CSTRIDE;
    float* scales = (float*)(ws + 58400768);          // 1696
    float* shifts = (float*)(ws + 58407552);          // 1696
    float* xf     = (float*)(ws + 58479872);          // 12288 f32
    int*   flag   = (int*)  (ws + 58529024);          // 1
    int*   cnt    = (int*)  (ws + 58529280);          // 8 ints (fusion counters)
    int*   enc    = (int*)  (ws + 58529536);          // 512 ints (encoded global max)

    const int Cin[4]  = {3, 96, 192, 384};
    const int Co[4]   = {96, 192, 384, 768};
    const int ooff[4] = {0, 96, 288, 672};
    const int soff[5] = {0, 96, 288, 672, 1440};
    const int woff[4] = {0, WOFF_L1, WOFF_L2, WOFF_L3};   // weight plane offsets (layers 1..3 used)

    hipLaunchKernelGGL(k_init, dim3(425), dim3(256), 0, stream, x, flag, xf, slots, cnt, enc);
    hipLaunchKernelGGL(k_knn, dim3(NPTS), dim3(256), 0, stream, xf, idx);
    hipLaunchKernelGGL(k_wt_all, dim3((WTOTAL + 255) / 256), dim3(256), 0, stream,
                       d_in[4], d_in[7], d_in[10], d_in[13], flag, Whall, Wlall);

    const float invcnt_edge = 1.f / (float)(NPTS * KNB);
    for (int L = 0; L < 4; L++) {
        const void* g  = d_in[2 + 3 * L];
        const void* bb = d_in[3 + 3 * L];
        int N2 = 2 * Co[L];
        if (L == 0) {
            hipLaunchKernelGGL(k_l0, dim3((NPTS * 192 + 255) / 256), dim3(256), 0, stream,
                               xf, d_in[1], flag, Ub, Vf);
        } else if (L < 3) {
            // skinny GEMMs: 64x64 tile, high co-residency
            hipLaunchKernelGGL((k_gemm_mfma<64, 64>), dim3(N2 / 64, NPTS / 64, 1), dim3(256), 0, stream,
                               fch, fcl, FCATC, ooff[L - 1], Whall + woff[L], Wlall + woff[L], Cin[L],
                               Ub, Vf, Co[L], 0, Cin[L], 0);
        } else {
            // wide GEMM: 128x64 tile -> 768 blocks (3/CU), 48 KiB LDS, 2-phase pipeline
            hipLaunchKernelGGL((k_gemm_mfma<128, 64>), dim3(N2 / 64, NPTS / 128, 1), dim3(256), 0, stream,
                               fch, fcl, FCATC, ooff[L - 1], Whall + woff[L], Wlall + woff[L], Cin[L],
                               Ub, Vf, Co[L], 0, Cin[L], 0);
        }
        int nchunks = ((Co[L] / 2) + 255) / 256;
        hipLaunchKernelGGL(k_gather, dim3(NPTS / PBATCH, nchunks), dim3(256), 0, stream,
                           Ub, Vf, idx, fch, fcl, ssum + soff[L], ssq + soff[L], Co[L], ooff[L],
                           g, bb, flag, scales + soff[L], shifts + soff[L], invcnt_edge,
                           cnt + L, (NPTS / PBATCH) * nchunks);
        hipLaunchKernelGGL(k_apply, dim3(NPTS), dim3(256), 0, stream,
                           Vf, scales + soff[L], shifts + soff[L], fch, fcl, Co[L], ooff[L]);
    }

    // final 1440 -> 256: split-K x5 into disjoint planes (128x64 tile -> 640 blocks, 2.5/CU),
    // then fused reduce+stats, then fused feats+globalmax
    hipLaunchKernelGGL((k_gemm_mfma<128, 64>), dim3(256 / 64, NPTS / 128, 5), dim3(256), 0, stream,
                       fch, fcl, FCATC, 0, Whall + WOFF_F, Wlall + WOFF_F, FCATC,
                       (bf16*)nullptr, part, 0, 256, 288, NPTS * 256);
    hipLaunchKernelGGL(k_stats_final, dim3(256), dim3(256), 0, stream, part, Y4, ssum + soff[4], ssq + soff[4]);
    hipLaunchKernelGGL(k_feats, dim3(128), dim3(256), 0, stream, Y4, ssum + soff[4], ssq + soff[4],
                       d_in[14], d_in[15], flag, d_out, enc, cnt + 4);
}

// Round 7
// 318.722 us; speedup vs baseline: 2.3260x; 2.3260x over previous
//
#include <hip/hip_runtime.h>
#include <hip/hip_bf16.h>

#define BATCH 2
#define NPB   2048
#define NPTS  4096   // BATCH*NPB
#define KNB   27
#define FCATC 1440
#define CSTRIDE 1696   // channel stride for slot partial sums (1440 + 256)
#define NSLOT 32
#define PBATCH 4       // points per gather block (atomic-traffic reduction)

// weight-plane segment offsets (elements): layer1 2*192x96, layer2 2*384x192, layer3 2*768x384, final 256x1440
#define WOFF_L1 0
#define WOFF_L2 36864
#define WOFF_L3 184320
#define WOFF_F  774144
#define WTOTAL  1142784

typedef __hip_bfloat16 bf16;
typedef __attribute__((ext_vector_type(8))) short short8;   // 8 bf16 = 4 VGPRs (MFMA A/B frag)
typedef __attribute__((ext_vector_type(4))) float f32x4;    // MFMA C/D frag
typedef __attribute__((ext_vector_type(2))) short s16x2;    // 2 bf16 = 4B vector

__device__ __forceinline__ float b2f(bf16 v) { return __bfloat162float(v); }

// split fp32 into hi/lo bf16 pair (hi + lo ~ 16 mantissa bits)
__device__ __forceinline__ void split_bf16(float v, bf16& h, bf16& l) {
    h = __float2bfloat16(v);
    l = __float2bfloat16(v - b2f(h));
}

// load input element i from buffer p whose dtype is fp32 (f32=1) or bf16 (f32=0)
__device__ __forceinline__ float ldin(const void* p, size_t i, int f32) {
    return f32 ? ((const float*)p)[i] : b2f(((const bf16*)p)[i]);
}

// async global->LDS 16B: lane writes lds_base + lane*16 (wave-uniform base, per-lane global)
__device__ __forceinline__ void gl16(const bf16* g, bf16* l) {
    __builtin_amdgcn_global_load_lds(
        (const __attribute__((address_space(1))) unsigned int*)g,
        (__attribute__((address_space(3))) unsigned int*)l,
        16, 0, 0);
}

// ---------------- init: zero slot accumulators + dtype-detect + convert x (fused) ----------------
__global__ void k_init(const void* __restrict__ x, int* __restrict__ flag,
                       float* __restrict__ xf, float* __restrict__ slots) {
    if (blockIdx.x < 424) {
        slots[blockIdx.x * 256 + threadIdx.x] = 0.f;
        return;
    }
    __shared__ int s;
    if (threadIdx.x == 0) s = 0;
    __syncthreads();
    const bf16* xb = (const bf16*)x;
    int local = 0;
    for (int i = threadIdx.x; i < NPTS * 3; i += 256) {
        float v = b2f(xb[i]);
        if (!(fabsf(v) < 1e4f)) local = 1;   // catches NaN/Inf/huge -> underlying fp32
    }
    if (local) s = 1;
    __syncthreads();
    int f32 = s;
    if (threadIdx.x == 0) flag[0] = f32;
    for (int i = threadIdx.x; i < NPTS * 3; i += 256) xf[i] = ldin(x, i, f32);
}

// ---------------- KNN via 2-pass radix-select (16-bit prefix) + tie resolution ----------------
__global__ __launch_bounds__(256) void k_knn(const float* __restrict__ x, int* __restrict__ idx) {
    __shared__ uint hist4[4][260];   // per-wave copies, padded
    __shared__ uint hist[256];
    __shared__ uint tkey[NPB];
    __shared__ int  tix[NPB];
    __shared__ uint s_phigh;
    __shared__ int  s_rem, s_outcnt, s_tiecnt;

    int bn = blockIdx.x, b = bn >> 11, n = bn & (NPB - 1);
    int tid = threadIdx.x;
    int wv = tid >> 6;
    const float* xb = x + (size_t)b * NPB * 3;
    float cx = xb[n * 3 + 0], cy = xb[n * 3 + 1], cz = xb[n * 3 + 2];
    float cc = cx * cx + cy * cy + cz * cz;

    uint u[8];
    #pragma unroll
    for (int j = 0; j < 8; j++) {
        int m = j * 256 + tid;
        float mx = xb[m * 3 + 0], my = xb[m * 3 + 1], mz = xb[m * 3 + 2];
        float d = 2.f * (cx * mx + cy * my + cz * mz) - cc - (mx * mx + my * my + mz * mz);
        uint s = __float_as_uint(d);
        u[j] = (s & 0x80000000u) ? ~s : (s | 0x80000000u);
    }
    if (tid == 0) { s_phigh = 0; s_rem = KNB; s_outcnt = 0; s_tiecnt = 0; }

    for (int pass = 0; pass < 2; pass++) {
        int shift = 24 - pass * 8;
        hist[tid] = 0;
        for (int i = tid; i < 4 * 260; i += 256) ((uint*)hist4)[i] = 0;
        __syncthreads();
        uint phigh = s_phigh;
        #pragma unroll
        for (int j = 0; j < 8; j++) {
            bool in = (pass == 0) || ((u[j] >> (shift + 8)) == phigh);
            if (in) atomicAdd(&hist4[wv][(u[j] >> shift) & 0xFFu], 1u);
        }
        __syncthreads();
        hist[tid] = hist4[0][tid] + hist4[1][tid] + hist4[2][tid] + hist4[3][tid];
        __syncthreads();
        if (tid < 64) {
            int L = tid;
            uint c0 = hist[L * 4 + 0], c1 = hist[L * 4 + 1], c2 = hist[L * 4 + 2], c3 = hist[L * 4 + 3];
            uint s = c0 + c1 + c2 + c3;
            uint acc = s;
            #pragma unroll
            for (int off = 1; off < 64; off <<= 1) {
                uint t = __shfl_down(acc, off);
                if (L + off < 64) acc += t;
            }
            uint excl = acc - s;
            int rem = s_rem;
            if ((int)excl < rem && (int)acc >= rem) {
                uint cs[4] = { c0, c1, c2, c3 };
                uint cum = excl;
                int bsel = 0; uint hb = 0;
                #pragma unroll
                for (int q = 3; q >= 0; q--) {
                    if ((int)cum < rem && (int)(cum + cs[q]) >= rem && hb == 0u && bsel == 0) {
                        bsel = L * 4 + q; hb = cs[q]; cum += cs[q];
                    } else if (bsel == 0 && hb == 0u) {
                        cum += cs[q];
                    }
                }
                int strictlyAbove = (int)(cum - hb);
                s_rem = rem - strictlyAbove;
                s_phigh = (phigh << 8) | (uint)bsel;
            }
        }
        __syncthreads();
    }

    uint T16 = s_phigh;   // 16-bit prefix of the 27th-largest key
    #pragma unroll
    for (int j = 0; j < 8; j++) {
        int m = j * 256 + tid;
        uint hi = u[j] >> 16;
        if (hi > T16) {
            int p = atomicAdd(&s_outcnt, 1);
            idx[bn * KNB + p] = b * NPB + m;
        } else if (hi == T16) {
            int p = atomicAdd(&s_tiecnt, 1);
            tkey[p] = u[j];
            tix[p] = m;
        }
    }
    __syncthreads();
    int outcnt = s_outcnt, rem = s_rem, tiecnt = s_tiecnt;
    if (tiecnt == rem) {
        if (tid < rem) idx[bn * KNB + outcnt + tid] = b * NPB + tix[tid];
    } else if (tid == 0) {
        for (int t = 0; t < rem; t++) {
            int bi = 0;
            for (int q = 1; q < tiecnt; q++)
                if (tkey[q] > tkey[bi] || (tkey[q] == tkey[bi] && tix[q] < tix[bi])) bi = q;
            idx[bn * KNB + outcnt + t] = b * NPB + tix[bi];
            tkey[bi] = 0; tix[bi] = 0x7fffffff;
        }
    }
}

// ---------------- layer0 direct: u -> Ub bf16, v -> Vf f32 (Co=96) ----------------
__global__ void k_l0(const float* __restrict__ xf, const void* __restrict__ W,
                     const int* __restrict__ flag, bf16* __restrict__ Ub, float* __restrict__ Vf) {
    int i = blockIdx.x * 256 + threadIdx.x;
    if (i >= NPTS * 192) return;
    int bn = i / 192, o = i % 192;
    int f32 = flag[0];
    float x0 = xf[bn * 3 + 0], x1 = xf[bn * 3 + 1], x2 = xf[bn * 3 + 2];
    if (o < 96) {
        float r = x0 * ldin(W, o * 6 + 0, f32) + x1 * ldin(W, o * 6 + 1, f32) + x2 * ldin(W, o * 6 + 2, f32);
        Ub[(size_t)bn * 96 + o] = __float2bfloat16(r);
    } else {
        int oo = o - 96;
        float w0 = ldin(W, oo * 6 + 3, f32) - ldin(W, oo * 6 + 0, f32);
        float w1 = ldin(W, oo * 6 + 4, f32) - ldin(W, oo * 6 + 1, f32);
        float w2 = ldin(W, oo * 6 + 5, f32) - ldin(W, oo * 6 + 2, f32);
        Vf[(size_t)bn * 96 + oo] = x0 * w0 + x1 * w1 + x2 * w2;
    }
}

// ---------------- ALL weight transforms in one kernel -> contiguous hi/lo planes ----------------
__global__ void k_wt_all(const void* __restrict__ W1, const void* __restrict__ W2,
                         const void* __restrict__ W3, const void* __restrict__ W4,
                         const int* __restrict__ flag,
                         bf16* __restrict__ Wh, bf16* __restrict__ Wl) {
    int i = blockIdx.x * 256 + threadIdx.x;
    if (i >= WTOTAL) return;
    int f32 = flag[0];
    float w;
    if (i < WOFF_L2) {                     // layer1: Cin=96, Co=192, 2Cin=192
        int row = i / 96, c = i % 96;
        w = (row < 192) ? ldin(W1, (size_t)row * 192 + c, f32)
                        : ldin(W1, (size_t)(row - 192) * 192 + 96 + c, f32)
                          - ldin(W1, (size_t)(row - 192) * 192 + c, f32);
    } else if (i < WOFF_L3) {              // layer2: Cin=192, Co=384, 2Cin=384
        int j = i - WOFF_L2;
        int row = j / 192, c = j % 192;
        w = (row < 384) ? ldin(W2, (size_t)row * 384 + c, f32)
                        : ldin(W2, (size_t)(row - 384) * 384 + 192 + c, f32)
                          - ldin(W2, (size_t)(row - 384) * 384 + c, f32);
    } else if (i < WOFF_F) {               // layer3: Cin=384, Co=768, 2Cin=768
        int j = i - WOFF_L3;
        int row = j / 384, c = j % 384;
        w = (row < 768) ? ldin(W3, (size_t)row * 768 + c, f32)
                        : ldin(W3, (size_t)(row - 768) * 768 + 384 + c, f32)
                          - ldin(W3, (size_t)(row - 768) * 768 + c, f32);
    } else {                               // final: 256 x 1440 direct
        int j = i - WOFF_F;
        w = ldin(W4, j, f32);
    }
    bf16 h, l; split_bf16(w, h, l);
    Wh[i] = h; Wl[i] = l;
}

// ---------------- split-precision MFMA GEMM: C = (Ah+Al) * (Bh+Bl)^T, ~fp32 accuracy ----------------
// Asymmetric tile TM x TN (128x64 for wide layers -> 768/640 blocks, 2.5-3/CU; 64x64 skinny).
// 2-phase pipeline: double-buffered LDS, prefetch next K-step's gl16 BEFORE computing current,
// ONE __syncthreads per step. Bank-conflict fix (rule #21, both-sides): source takes global
// 16B-slot (slot ^ ((row>>1)&3)); frag read XORs the same -> 8-way conflict becomes 2-way (free).
// Cosplit>0: cols [0,Cosplit)->Cu bf16, rest->Cv f32; Cosplit==0: f32 split-K plane write (Cz).
template<int TM, int TN>
__global__ __launch_bounds__(256) void k_gemm_mfma(const bf16* __restrict__ Ah, const bf16* __restrict__ Al,
                                                   int lda, int aoff,
                                                   const bf16* __restrict__ Bh, const bf16* __restrict__ Bl,
                                                   int K, bf16* __restrict__ Cu, float* __restrict__ Cv,
                                                   int Cosplit, int ldc, int ksz, int zstride) {
    constexpr int FRM  = TM / 32;          // A frags per wave
    constexpr int FRN  = TN / 32;          // B frags per wave
    constexpr int ISSA = TM / 64;          // gl16 issues per A array per thread
    constexpr int ISSB = TN / 64;          // gl16 issues per B array per thread
    constexpr int MY   = (NPTS / TM) / 8;  // m-tiles per stripe (pow2)
    __shared__ __align__(16) bf16 Ash[2][TM][32];   // linear (global_load_lds needs contiguous dest)
    __shared__ __align__(16) bf16 Asl[2][TM][32];
    __shared__ __align__(16) bf16 Bsh[2][TN][32];
    __shared__ __align__(16) bf16 Bsl[2][TN][32];
    int tid = threadIdx.x;
    int wave = tid >> 6, lane = tid & 63;
    int wm = wave >> 1, wn = wave & 1;
    int quad = lane >> 4, l15 = lane & 15;
    int Lxy = blockIdx.y * gridDim.x + blockIdx.x;
    int stripe = Lxy & 7;
    int w = Lxy >> 3;
    int mb = stripe * MY + (w & (MY - 1));
    int nb = w / MY;
    int m0 = mb * TM, n0 = nb * TN;
    int kbase = blockIdx.z * ksz;
    float* Cz = Cv + (size_t)blockIdx.z * zstride;

    // staging geometry: chunk c covers LDS row c>>2, physical 16B slot c&3; the SOURCE takes
    // global slot (c&3)^((row>>1)&3) so that a swizzled frag read is conflict-free.
    int ra_s[ISSA], ca_s[ISSA];
    #pragma unroll
    for (int i = 0; i < ISSA; i++) {
        int c = wave * 64 + lane + i * 256;
        ra_s[i] = c >> 2;
        ca_s[i] = (((c & 3) ^ ((c >> 3) & 3)) << 3);
    }
    int rb_s[ISSB], cb_s[ISSB];
    #pragma unroll
    for (int i = 0; i < ISSB; i++) {
        int c = wave * 64 + lane + i * 256;
        rb_s[i] = c >> 2;
        cb_s[i] = (((c & 3) ^ ((c >> 3) & 3)) << 3);
    }

    auto STAGE = [&](int buf, int k0) {
        #pragma unroll
        for (int i = 0; i < ISSA; i++) {
            size_t ga = (size_t)(m0 + ra_s[i]) * lda + aoff + k0 + ca_s[i];
            gl16(Ah + ga, &Ash[buf][0][0] + wave * 512 + i * 2048);   // wave-uniform LDS base
            gl16(Al + ga, &Asl[buf][0][0] + wave * 512 + i * 2048);
        }
        #pragma unroll
        for (int i = 0; i < ISSB; i++) {
            size_t gb = (size_t)(n0 + rb_s[i]) * K + k0 + cb_s[i];
            gl16(Bh + gb, &Bsh[buf][0][0] + wave * 512 + i * 2048);
            gl16(Bl + gb, &Bsl[buf][0][0] + wave * 512 + i * 2048);
        }
    };

    int nsteps = ksz >> 5;
    f32x4 acc[FRM][FRN] = {};
    STAGE(0, kbase);
    __syncthreads();
    int cur = 0;
    for (int t = 0; t < nsteps; t++) {
        if (t + 1 < nsteps) STAGE(cur ^ 1, kbase + ((t + 1) << 5));   // prefetch next step
        short8 ahf[FRM], alf[FRM], bhf[FRN], blf[FRN];
        #pragma unroll
        for (int mt = 0; mt < FRM; mt++) {
            int rr = wm * (TM / 2) + mt * 16 + l15;
            int qs = (quad ^ ((rr >> 1) & 3)) * 8;
            ahf[mt] = *(const short8*)&Ash[cur][rr][qs];
            alf[mt] = *(const short8*)&Asl[cur][rr][qs];
        }
        #pragma unroll
        for (int nt = 0; nt < FRN; nt++) {
            int rr = wn * (TN / 2) + nt * 16 + l15;
            int qs = (quad ^ ((rr >> 1) & 3)) * 8;
            bhf[nt] = *(const short8*)&Bsh[cur][rr][qs];
            blf[nt] = *(const short8*)&Bsl[cur][rr][qs];
        }
        #pragma unroll
        for (int mt = 0; mt < FRM; mt++) {
            #pragma unroll
            for (int nt = 0; nt < FRN; nt++) {
                acc[mt][nt] = __builtin_amdgcn_mfma_f32_16x16x32_bf16(ahf[mt], blf[nt], acc[mt][nt], 0, 0, 0);
                acc[mt][nt] = __builtin_amdgcn_mfma_f32_16x16x32_bf16(alf[mt], bhf[nt], acc[mt][nt], 0, 0, 0);
                acc[mt][nt] = __builtin_amdgcn_mfma_f32_16x16x32_bf16(ahf[mt], bhf[nt], acc[mt][nt], 0, 0, 0);
            }
        }
        __syncthreads();   // drains prefetch vmcnt + lgkm; orders buffer reuse
        cur ^= 1;
    }
    #pragma unroll
    for (int mt = 0; mt < FRM; mt++) {
        #pragma unroll
        for (int nt = 0; nt < FRN; nt++) {
            int col = n0 + wn * (TN / 2) + nt * 16 + l15;
            #pragma unroll
            for (int i = 0; i < 4; i++) {
                int row = m0 + wm * (TM / 2) + mt * 16 + quad * 4 + i;
                if (Cosplit > 0) {
                    if (col < Cosplit) Cu[(size_t)row * Cosplit + col] = __float2bfloat16(acc[mt][nt][i]);
                    else               Cv[(size_t)row * Cosplit + col - Cosplit] = acc[mt][nt][i];
                } else {
                    Cz[(size_t)row * ldc + col] = acc[mt][nt][i];
                }
            }
        }
    }
}

// ---------------- fused gather: 2 channels/thread, XCD-batch partition ----------------
// With the observed round-robin block->XCD mapping (bid%8), XCDs 0-3 handle batch 0 and XCDs 4-7
// batch 1 -> each XCD's hot Ub slice halves (Co=768: 3.1 MB <= 4 MiB L2, was 6.3 MB thrash).
// Bijective remap of low-10 bits of L: [b9..b3|b2|b1b0] -> mid | batch | 128-group. NO fences,
// NO cross-block counters (R6 lesson: device-scope threadfence per block cost 40x).
__global__ __launch_bounds__(256) void k_gather(const bf16* __restrict__ Ub, float* __restrict__ Vf,
                                                const int* __restrict__ idx,
                                                bf16* __restrict__ fch, bf16* __restrict__ fcl,
                                                float* __restrict__ ssum, float* __restrict__ ssq,
                                                int Co, int out_off) {
    __shared__ int srow[PBATCH * KNB];
    int tid = threadIdx.x;
    int L = blockIdx.y * gridDim.x + blockIdx.x;
    int batch = (L >> 2) & 1;                            // XCD-pair partition (bid%8: 0-3 vs 4-7)
    int pg = batch * 512 + (L & 3) * 128 + ((L >> 3) & 127);
    int chunk = L >> 10;                                 // channel-pair chunk
    int p0 = pg * PBATCH;
    if (tid < PBATCH * KNB) srow[tid] = idx[p0 * KNB + tid] * Co;
    __syncthreads();
    int P = Co >> 1;
    int op = chunk * 256 + tid;
    if (op >= P) return;
    int o = op * 2;
    int slot = pg & (NSLOT - 1);
    float s0 = 0.f, s1 = 0.f, q0 = 0.f, q1 = 0.f;
    #pragma unroll 1
    for (int p = 0; p < PBATCH; p++) {
        int bn = p0 + p;
        float2 vv = *(const float2*)&Vf[(size_t)bn * Co + o];
        float ymax0 = -INFINITY, ymax1 = -INFINITY, ymin0 = INFINITY, ymin1 = INFINITY;
        #pragma unroll
        for (int k = 0; k < KNB; k++) {
            uint wb = *(const uint*)&Ub[(size_t)srow[p * KNB + k] + o];
            float y0 = __uint_as_float(wb << 16) + vv.x;
            float y1 = __uint_as_float(wb & 0xffff0000u) + vv.y;
            ymax0 = fmaxf(ymax0, y0); ymin0 = fminf(ymin0, y0); s0 += y0; q0 += y0 * y0;
            ymax1 = fmaxf(ymax1, y1); ymin1 = fminf(ymin1, y1); s1 += y1; q1 += y1 * y1;
        }
        size_t fi = (size_t)bn * FCATC + out_off + o;
        bf16 hh[2], ll[2];
        split_bf16(ymax0, hh[0], ll[0]);
        split_bf16(ymax1, hh[1], ll[1]);
        *(s16x2*)&fch[fi] = *(const s16x2*)hh;
        *(s16x2*)&fcl[fi] = *(const s16x2*)ll;
        *(float2*)&Vf[(size_t)bn * Co + o] = make_float2(ymin0, ymin1);   // stash ymin
    }
    atomicAdd(&ssum[slot * CSTRIDE + o + 0], s0);
    atomicAdd(&ssum[slot * CSTRIDE + o + 1], s1);
    atomicAdd(&ssq [slot * CSTRIDE + o + 0], q0);
    atomicAdd(&ssq [slot * CSTRIDE + o + 1], q1);
}

// ---------------- scale/shift from 32-slot partials (edge layers) ----------------
__global__ void k_scaleshift(const float* __restrict__ ssum, const float* __restrict__ ssq,
                             const void* __restrict__ g, const void* __restrict__ bb,
                             const int* __restrict__ flag,
                             float* __restrict__ scale, float* __restrict__ shift, int Co, float invcnt) {
    int o = blockIdx.x * 256 + threadIdx.x;
    if (o >= Co) return;
    int f32 = flag[0];
    float s = 0.f, q = 0.f;
    for (int c = 0; c < NSLOT; c++) { s += ssum[c * CSTRIDE + o]; q += ssq[c * CSTRIDE + o]; }
    float mean = s * invcnt;
    float var = q * invcnt - mean * mean;
    float sc = ldin(g, o, f32) * rsqrtf(var + 1e-5f);
    scale[o] = sc;
    shift[o] = ldin(bb, o, f32) - mean * sc;
}

// ---------------- apply BN + lrelu to the pooled value (in place in fcat hi/lo) ----------------
__global__ __launch_bounds__(256) void k_apply(const float* __restrict__ Vf,
                                               const float* __restrict__ scale, const float* __restrict__ shift,
                                               bf16* __restrict__ fch, bf16* __restrict__ fcl,
                                               int Co, int out_off) {
    int bn = blockIdx.x;
    for (int o = threadIdx.x; o < Co; o += 256) {
        float sc = scale[o], sh = shift[o];
        size_t fi = (size_t)bn * FCATC + out_off + o;
        float y = (sc >= 0.f) ? (b2f(fch[fi]) + b2f(fcl[fi]))
                              : Vf[(size_t)bn * Co + o];           // ymin if negative scale
        float z = sc * y + sh;
        z = (z >= 0.f) ? z : 0.2f * z;
        bf16 h, l; split_bf16(z, h, l);
        fch[fi] = h; fcl[fi] = l;
    }
}

// ---------------- final: reduce 5 split-K planes -> Y4 + BN stats (256 blocks x 16 points) ----------------
__global__ void k_stats_final(const float* __restrict__ part, float* __restrict__ Y,
                              float* __restrict__ ssum, float* __restrict__ ssq) {
    int o = threadIdx.x;
    int p0 = blockIdx.x * 16;
    int slot = blockIdx.x & (NSLOT - 1);
    const size_t PL = (size_t)NPTS * 256;
    float s = 0, q = 0;
    for (int p = 0; p < 16; p++) {
        size_t i = (size_t)(p0 + p) * 256 + o;
        float y = part[i] + part[i + PL] + part[i + 2 * PL] + part[i + 3 * PL] + part[i + 4 * PL];
        Y[i] = y;
        s += y; q += y * y;
    }
    atomicAdd(&ssum[slot * CSTRIDE + o], s);
    atomicAdd(&ssq [slot * CSTRIDE + o], q);
}

// ---------------- feats: fused final scale/shift + BN + lrelu + per-chunk max (128 blocks) ----------------
__global__ void k_feats(const float* __restrict__ Y, const float* __restrict__ ssum,
                        const float* __restrict__ ssq, const void* __restrict__ g,
                        const void* __restrict__ bb, const int* __restrict__ flag,
                        void* __restrict__ out, float* __restrict__ partial) {
    int o = threadIdx.x;
    int chunk = blockIdx.x;
    int bn0 = chunk * 32;
    int f32 = flag[0];
    float s = 0.f, q = 0.f;
    for (int c = 0; c < NSLOT; c++) { s += ssum[c * CSTRIDE + o]; q += ssq[c * CSTRIDE + o]; }
    float mean = s * (1.f / (float)NPTS);
    float var = q * (1.f / (float)NPTS) - mean * mean;
    float sc = ldin(g, o, f32) * rsqrtf(var + 1e-5f);
    float sh = ldin(bb, o, f32) - mean * sc;
    float best = -INFINITY;
    for (int i = 0; i < 32; i++) {
        int bn = bn0 + i;
        float z = sc * Y[(size_t)bn * 256 + o] + sh;
        z = (z >= 0.f) ? z : 0.2f * z;
        size_t oi = (size_t)BATCH * 256 + (size_t)bn * 256 + o;
        if (f32) ((float*)out)[oi] = z;
        else     ((bf16*)out)[oi] = __float2bfloat16(z);
        best = fmaxf(best, z);
    }
    partial[chunk * 256 + o] = best;
}

__global__ void k_gmax(const float* __restrict__ partial, void* __restrict__ out, const int* __restrict__ flag) {
    int o = threadIdx.x;
    int b = blockIdx.x;
    float best = -INFINITY;
    for (int c = 0; c < 64; c++) best = fmaxf(best, partial[(b * 64 + c) * 256 + o]);
    if (flag[0]) ((float*)out)[b * 256 + o] = best;
    else         ((bf16*)out)[b * 256 + o] = __float2bfloat16(best);
}

// ---------------- launch ----------------
extern "C" void kernel_launch(void* const* d_in, const int* in_sizes, int n_in,
                              void* d_out, int out_size, void* d_ws, size_t ws_size,
                              hipStream_t stream) {
    const void* x = d_in[0];

    char* ws = (char*)d_ws;
    int*   idx    = (int*)  (ws + 0);                 // 4096*27 int
    bf16*  Ub     = (bf16*) (ws + 442368);            // 4096 x 768 bf16 (u, 6.29 MB)
    float* Vf     = (float*)(ws + 6733824);           // 4096 x 768 f32 (v/ymin, 12.58 MB)
    float* part   = (float*)(ws + 442368);            // reused after layers: 5 x 4096 x 256 f32 (21 MB)
    bf16*  fch    = (bf16*) (ws + 25608192);          // 4096 x 1440 bf16 (hi)
    bf16*  fcl    = (bf16*) (ws + 37404672);          // 4096 x 1440 bf16 (lo)
    float* Y4     = (float*)(ws + 49201152);          // 4096 x 256 f32
    bf16*  Whall  = (bf16*) (ws + 53395456);          // WTOTAL bf16 (hi planes, 2.29 MB)
    bf16*  Wlall  = (bf16*) (ws + 55681024);          // WTOTAL bf16 (lo planes)
    float* slots  = (float*)(ws + 57966592);          // 2 x 32 x 1696 f32 (434176 B)
    float* ssum   = slots;
    float* ssq    = slots + NSLOT * CSTRIDE;
    float* scales = (float*)(ws + 58400768);          // 1696
    float* shifts = (float*)(ws + 58407552);          // 1696
    float* partial= (float*)(ws + 442368);            // 128 x 256 f32, reuses dead part region (post stats)
    float* xf     = (float*)(ws + 58479872);          // 12288 f32
    int*   flag   = (int*)  (ws + 58529024);          // 1

    const int Cin[4]  = {3, 96, 192, 384};
    const int Co[4]   = {96, 192, 384, 768};
    const int ooff[4] = {0, 96, 288, 672};
    const int soff[5] = {0, 96, 288, 672, 1440};
    const int woff[4] = {0, WOFF_L1, WOFF_L2, WOFF_L3};   // weight plane offsets (layers 1..3 used)

    hipLaunchKernelGGL(k_init, dim3(425), dim3(256), 0, stream, x, flag, xf, slots);
    hipLaunchKernelGGL(k_knn, dim3(NPTS), dim3(256), 0, stream, xf, idx);
    hipLaunchKernelGGL(k_wt_all, dim3((WTOTAL + 255) / 256), dim3(256), 0, stream,
                       d_in[4], d_in[7], d_in[10], d_in[13], flag, Whall, Wlall);

    const float invcnt_edge = 1.f / (float)(NPTS * KNB);
    for (int L = 0; L < 4; L++) {
        const void* g  = d_in[2 + 3 * L];
        const void* bb = d_in[3 + 3 * L];
        int N2 = 2 * Co[L];
        if (L == 0) {
            hipLaunchKernelGGL(k_l0, dim3((NPTS * 192 + 255) / 256), dim3(256), 0, stream,
                               xf, d_in[1], flag, Ub, Vf);
        } else if (L < 3) {
            // skinny GEMMs: 64x64 tile, high co-residency
            hipLaunchKernelGGL((k_gemm_mfma<64, 64>), dim3(N2 / 64, NPTS / 64, 1), dim3(256), 0, stream,
                               fch, fcl, FCATC, ooff[L - 1], Whall + woff[L], Wlall + woff[L], Cin[L],
                               Ub, Vf, Co[L], 0, Cin[L], 0);
        } else {
            // wide GEMM: 128x64 tile -> 768 blocks (3/CU), 48 KiB LDS, 2-phase pipeline
            hipLaunchKernelGGL((k_gemm_mfma<128, 64>), dim3(N2 / 64, NPTS / 128, 1), dim3(256), 0, stream,
                               fch, fcl, FCATC, ooff[L - 1], Whall + woff[L], Wlall + woff[L], Cin[L],
                               Ub, Vf, Co[L], 0, Cin[L], 0);
        }
        int nchunks = ((Co[L] / 2) + 255) / 256;
        hipLaunchKernelGGL(k_gather, dim3(NPTS / PBATCH, nchunks), dim3(256), 0, stream,
                           Ub, Vf, idx, fch, fcl, ssum + soff[L], ssq + soff[L], Co[L], ooff[L]);
        hipLaunchKernelGGL(k_scaleshift, dim3((Co[L] + 255) / 256), dim3(256), 0, stream,
                           ssum + soff[L], ssq + soff[L], g, bb, flag,
                           scales + soff[L], shifts + soff[L], Co[L], invcnt_edge);
        hipLaunchKernelGGL(k_apply, dim3(NPTS), dim3(256), 0, stream,
                           Vf, scales + soff[L], shifts + soff[L], fch, fcl, Co[L], ooff[L]);
    }

    // final 1440 -> 256: split-K x5 into disjoint planes (128x64 tile -> 640 blocks, 2.5/CU),
    // then fused reduce+stats
    hipLaunchKernelGGL((k_gemm_mfma<128, 64>), dim3(256 / 64, NPTS / 128, 5), dim3(256), 0, stream,
                       fch, fcl, FCATC, 0, Whall + WOFF_F, Wlall + WOFF_F, FCATC,
                       (bf16*)nullptr, part, 0, 256, 288, NPTS * 256);
    hipLaunchKernelGGL(k_stats_final, dim3(256), dim3(256), 0, stream, part, Y4, ssum + soff[4], ssq + soff[4]);
    hipLaunchKernelGGL(k_feats, dim3(128), dim3(256), 0, stream, Y4, ssum + soff[4], ssq + soff[4],
                       d_in[14], d_in[15], flag, d_out, partial);
    hipLaunchKernelGGL(k_gmax, dim3(BATCH), dim3(256), 0, stream, partial, d_out, flag);
}